// Round 2
// baseline (1216.273 us; speedup 1.0000x reference)
//
#include <hip/hip_runtime.h>
#include <math.h>

// Problem constants: D=3, H=64, WIN=8, OUT=32, B=128, T=129
#define BB 128
#define TT 129
#define NSTEP 128
#define NW 16
#define WINW 8
#define OUTD 32
#define NB 2            // batches per block (independent work to fill latency stalls)

typedef _Float16 h2_t __attribute__((ext_vector_type(2)));

__device__ __forceinline__ float fast_rcp(float v){ return __builtin_amdgcn_rcpf(v); }
__device__ __forceinline__ float softplus_f(float v){ return fmaxf(v,0.f)+__logf(1.f+__expf(-fabsf(v))); }
__device__ __forceinline__ float sigmoid_f(float v){ return fast_rcp(1.f+__expf(-v)); }
__device__ __forceinline__ float tanh_f(float v){
    float ax=fminf(fabsf(v),15.f); float e=__expf(2.f*ax);
    float r=1.f-2.f*fast_rcp(e+1.f); return copysignf(r,v);
}
__device__ __forceinline__ float pack2(float a,float b){
    h2_t h; h.x=(_Float16)a; h.y=(_Float16)b; return __builtin_bit_cast(float,h);
}
__device__ __forceinline__ float dot2c(float wc,float ac,float acc){
    return __builtin_amdgcn_fdot2(__builtin_bit_cast(h2_t,wc),__builtin_bit_cast(h2_t,ac),acc,false);
}
__device__ __forceinline__ float dot2q(float4 wq,float4 aq,float acc){
    acc=dot2c(wq.x,aq.x,acc); acc=dot2c(wq.y,aq.y,acc);
    acc=dot2c(wq.z,aq.z,acc); acc=dot2c(wq.w,aq.w,acc); return acc;
}
#define DOT4(acc,Wv,Av) acc += (Wv).x*(Av).x + (Wv).y*(Av).y + (Wv).z*(Av).z + (Wv).w*(Av).w
#define PIN4(q) asm volatile("" : "+v"((q).x), "+v"((q).y), "+v"((q).z), "+v"((q).w))

// DPP cross-lane: VALU-speed (~4cyc) vs ds_swizzle-based __shfl_xor (~120cyc LDS-pipe)
#define DPPF(x,ctrl) __builtin_bit_cast(float, __builtin_amdgcn_update_dpp(0, __builtin_bit_cast(int,(x)), (ctrl), 0xF, 0xF, true))
__device__ __forceinline__ float dpp_xor1(float x){ return DPPF(x,0xB1); }   // quad_perm [1,0,3,2] (involution)
__device__ __forceinline__ float dpp_xor2(float x){ return DPPF(x,0x4E); }   // quad_perm [2,3,0,1] (involution)
__device__ __forceinline__ float dpp_hmir(float x){ return DPPF(x,0x141); }  // row_half_mirror: lane i <- (i&~7)+(7-(i&7))

__global__ __launch_bounds__(256, 1)
void ncde_solve(const float* __restrict__ ts, const float* __restrict__ x,
                const float* __restrict__ W0, const float* __restrict__ b0,
                const float* __restrict__ W1, const float* __restrict__ b1,
                const float* __restrict__ W2, const float* __restrict__ b2,
                const float* __restrict__ V0, const float* __restrict__ c0,
                const float* __restrict__ V1, const float* __restrict__ c1,
                const float* __restrict__ V2, const float* __restrict__ c2,
                const float* __restrict__ R, const float* __restrict__ rb,
                float* __restrict__ out)
{
    const int bA = blockIdx.x * NB;
    const int tid = threadIdx.x;
    const int row2 = tid >> 1, half = tid & 1;         // rows 0..127, K halved
    const int row4 = 128 + (tid >> 2), quad = tid & 3; // V2 rows 128..191, K quartered
    const int prow = tid >> 3, poct = tid & 7;         // projection

    __shared__ __align__(16) float RSh[OUTD*68];           // stride 68: kill bank conflicts
    __shared__ __align__(16) float ySh[NB][64], k1Sh[NB][64];
    __shared__ __align__(16) float yp[NB][32], y2p[NB][32];
    __shared__ __align__(16) float a0p[NB][64], a1p[NB][64];
    __shared__ __align__(16) float mp[NB][96];
    __shared__ __align__(16) float u0p[NB][3][64], u1p[NB][3][64];
    __shared__ float mSh[NB][192];
    __shared__ float JfSh[NB][3][192];
    __shared__ float slopesSh[NB][NW][6];
    __shared__ float dtsSh[NB][NSTEP];

    // ---- fp16-packed weight carriers in registers (shared across the NB batches) ----
    float4 v0p4[4];  // V0 half-row  (32 halves)
    float4 v1p4[8];  // V1 half-row  (64 halves)
    float4 v2p4[8];  // V2 rows 0..127 half-row (64 halves)
    float4 v2q4[4];  // V2 rows 128..191 quarter-row (32 halves), rotated groups
    {
        const float4* p0 = (const float4*)(V0 + row2*64 + half*32);
        #pragma unroll
        for (int k=0;k<4;k++){
            float4 a=p0[2*k], c=p0[2*k+1];
            float4 r; r.x=pack2(a.x,a.y); r.y=pack2(a.z,a.w); r.z=pack2(c.x,c.y); r.w=pack2(c.z,c.w);
            v0p4[k]=r;
        }
        const float4* p1 = (const float4*)(V1 + row2*128 + half*64);
        #pragma unroll
        for (int k=0;k<8;k++){
            float4 a=p1[2*k], c=p1[2*k+1];
            float4 r; r.x=pack2(a.x,a.y); r.y=pack2(a.z,a.w); r.z=pack2(c.x,c.y); r.w=pack2(c.z,c.w);
            v1p4[k]=r;
        }
        const float4* p2 = (const float4*)(V2 + row2*128 + half*64);
        #pragma unroll
        for (int k=0;k<8;k++){
            float4 a=p2[2*k], c=p2[2*k+1];
            float4 r; r.x=pack2(a.x,a.y); r.y=pack2(a.z,a.w); r.z=pack2(c.x,c.y); r.w=pack2(c.z,c.w);
            v2p4[k]=r;
        }
        #pragma unroll
        for (int j=0;j<4;j++){
            int g=(quad+j)&3;
            const float4* pg = (const float4*)(V2 + row4*128 + quad*32 + g*8);
            float4 a=pg[0], c=pg[1];
            float4 r; r.x=pack2(a.x,a.y); r.y=pack2(a.z,a.w); r.z=pack2(c.x,c.y); r.w=pack2(c.z,c.w);
            v2q4[j]=r;
        }
        #pragma unroll
        for (int k=0;k<4;k++) PIN4(v0p4[k]);
        #pragma unroll
        for (int k=0;k<8;k++) PIN4(v1p4[k]);
        #pragma unroll
        for (int k=0;k<8;k++) PIN4(v2p4[k]);
        #pragma unroll
        for (int k=0;k<4;k++) PIN4(v2q4[k]);
    }
    const float c0r = c0[row2], c1r = c1[row2], c2a = c2[row2], c2b = c2[row4];
    const float rbp = rb[prow];

    for (int i=tid; i<OUTD*64; i+=256) RSh[(i>>6)*68 + (i&63)] = R[i];
    for (int i=tid; i<NB*NSTEP; i+=256){
        int u=i>>7, k=i&127;
        const float* tsu = ts + (size_t)(bA+u)*TT;
        dtsSh[u][k] = tsu[k+1] - tsu[k];
    }

    // ---- log-signature slopes (NB*16 windows) ----
    if (tid < NB*NW) {
        const int u = tid>>4, wi = tid&15;
        const float* tsu = ts + (size_t)(bA+u)*TT;
        const float* xs = x + (size_t)((bA+u)*TT + wi*WINW)*3;
        float x0c[3] = {xs[0], xs[1], xs[2]};
        float prev[3] = {x0c[0], x0c[1], x0c[2]};
        float am01=0.f, am02=0.f, am12=0.f, am10=0.f, am20=0.f, am21=0.f;
        #pragma unroll
        for (int k=0;k<WINW;k++) {
            float cur[3] = {xs[(k+1)*3+0], xs[(k+1)*3+1], xs[(k+1)*3+2]};
            float rel[3], dv[3];
            #pragma unroll
            for (int c=0;c<3;c++){ rel[c]=prev[c]-x0c[c]; dv[c]=cur[c]-prev[c]; }
            am01 += rel[0]*dv[1]; am10 += rel[1]*dv[0];
            am02 += rel[0]*dv[2]; am20 += rel[2]*dv[0];
            am12 += rel[1]*dv[2]; am21 += rel[2]*dv[1];
            prev[0]=cur[0]; prev[1]=cur[1]; prev[2]=cur[2];
        }
        const float invden = 1.f/(tsu[(wi+1)*WINW] - tsu[wi*WINW]);
        slopesSh[u][wi][0] = (prev[0]-x0c[0])*invden;
        slopesSh[u][wi][1] = (prev[1]-x0c[1])*invden;
        slopesSh[u][wi][2] = (prev[2]-x0c[2])*invden;
        slopesSh[u][wi][3] = 0.5f*(am01-am10)*invden;
        slopesSh[u][wi][4] = 0.5f*(am02-am20)*invden;
        slopesSh[u][wi][5] = 0.5f*(am12-am21)*invden;
    }

    // ---- h0 = init_mlp(x[b,0,:]) for both batches (mSh/JfSh as scratch) ----
    for (int i=tid; i<NB*128; i+=256) {
        const int u = i>>7, r = i&127;
        const float* xb = x + (size_t)(bA+u)*TT*3;
        float acc = b0[r] + W0[r*3]*xb[0] + W0[r*3+1]*xb[1] + W0[r*3+2]*xb[2];
        mSh[u][r] = softplus_f(acc);
    }
    __syncthreads();
    for (int i=tid; i<NB*128; i+=256) {
        const int u = i>>7, r = i&127;
        float acc = b1[r];
        const float4* rw = (const float4*)(W1 + r*128);
        #pragma unroll 8
        for (int k=0;k<32;k++){ float4 wv=rw[k]; float4 av=*(const float4*)&mSh[u][4*k]; DOT4(acc,wv,av); }
        JfSh[u][0][r] = softplus_f(acc);
    }
    __syncthreads();
    if (tid < NB*64) {
        const int u = tid>>6, h = tid&63;
        float acc = b2[h];
        const float4* rw = (const float4*)(W2 + h*128);
        #pragma unroll 8
        for (int k=0;k<32;k++){ float4 wv=rw[k]; float4 av=*(const float4*)&JfSh[u][0][4*k]; DOT4(acc,wv,av); }
        ySh[u][h] = acc;
        float p = dpp_xor1(acc);
        if (!(h & 1)) yp[u][h>>1] = pack2(acc, p);
    }
    __syncthreads();

    // per-lane activation-derivative registers (per batch)
    float sig0r[NB], sig1r[NB], dtanA[NB], dtanB[NB];
    #pragma unroll
    for (int u=0;u<NB;++u){ sig0r[u]=0.f; sig1r[u]=0.f; dtanA[u]=0.f; dtanB[u]=0.f; }

    const int tlo = (tid < 128) ? 1 : 0;  // S6 skip-diagonal: which of {t0,t1} this half computes

    // ---- F(y) for both batches per stage; fp16 inner, fp32 feedback ----
    auto Feval = [&](int first, int step) {
        // S1: z0 = V0@y + c0
        {
            float z[NB];
            #pragma unroll
            for (int u=0;u<NB;++u){
                const float4* yb = (const float4*)(first ? yp[u] : y2p[u]) + half*4;
                float zA=0.f, zB=0.f;
                zA=dot2q(v0p4[0],yb[0],zA); zB=dot2q(v0p4[1],yb[1],zB);
                zA=dot2q(v0p4[2],yb[2],zA); zB=dot2q(v0p4[3],yb[3],zB);
                z[u]=zA+zB;
            }
            #pragma unroll
            for (int u=0;u<NB;++u){
                float zz = z[u] + dpp_xor1(z[u]) + c0r;
                float a = softplus_f(zz);
                sig0r[u] = sigmoid_f(zz);
                if (!half) ((_Float16*)a0p[u])[row2] = (_Float16)a;
            }
        }
        __syncthreads();
        // S2: z1 = V1@a0 + c1
        {
            float z[NB];
            #pragma unroll
            for (int u=0;u<NB;++u){
                const float4* ab = (const float4*)a0p[u] + half*8;
                float zA=0.f, zB=0.f;
                #pragma unroll
                for (int k=0;k<4;k++) zA=dot2q(v1p4[k],ab[k],zA);
                #pragma unroll
                for (int k=4;k<8;k++) zB=dot2q(v1p4[k],ab[k],zB);
                z[u]=zA+zB;
            }
            #pragma unroll
            for (int u=0;u<NB;++u){
                float zz = z[u] + dpp_xor1(z[u]) + c1r;
                float a = softplus_f(zz);
                sig1r[u] = sigmoid_f(zz);
                if (!half) ((_Float16*)a1p[u])[row2] = (_Float16)a;
            }
        }
        __syncthreads();
        // S3: z2 = V2@a1 + c2 ; m = tanh, dtan in regs
        {
            float z[NB], zq[NB];
            #pragma unroll
            for (int u=0;u<NB;++u){
                const float4* ab = (const float4*)a1p[u] + half*8;
                float zA=0.f, zB=0.f;
                #pragma unroll
                for (int k=0;k<4;k++) zA=dot2q(v2p4[k],ab[k],zA);
                #pragma unroll
                for (int k=4;k<8;k++) zB=dot2q(v2p4[k],ab[k],zB);
                z[u]=zA+zB;
                const float4* a4 = (const float4*)a1p[u];
                float q=0.f;
                #pragma unroll
                for (int j=0;j<4;j++) q=dot2q(v2q4[j], a4[quad*4 + ((quad+j)&3)], q);
                zq[u]=q;
            }
            #pragma unroll
            for (int u=0;u<NB;++u){
                float zz = z[u] + dpp_xor1(z[u]) + c2a;
                float mm = tanh_f(zz);
                dtanA[u] = 1.f - mm*mm;
                if (!half){ mSh[u][row2]=mm; ((_Float16*)mp[u])[row2]=(_Float16)mm; }
                float q = zq[u] + dpp_xor1(zq[u]);
                q += dpp_xor2(q);
                q += c2b;
                float mq = tanh_f(q);
                dtanB[u] = 1.f - mq*mq;
                if (!quad){ mSh[u][row4]=mq; ((_Float16*)mp[u])[row4]=(_Float16)mq; }
            }
        }
        __syncthreads();
        // S4: u0[d] = sig0 * (V0 @ m[d])
        {
            float t[NB][3];
            #pragma unroll
            for (int u=0;u<NB;++u){
                const float4* m0 = (const float4*)mp[u] + half*4;
                const float4* m1 = (const float4*)mp[u] + 8  + half*4;
                const float4* m2 = (const float4*)mp[u] + 16 + half*4;
                float t0=0.f,t1=0.f,t2=0.f;
                #pragma unroll
                for (int k=0;k<4;k++){ t0=dot2q(v0p4[k],m0[k],t0); t1=dot2q(v0p4[k],m1[k],t1); t2=dot2q(v0p4[k],m2[k],t2); }
                t[u][0]=t0; t[u][1]=t1; t[u][2]=t2;
            }
            #pragma unroll
            for (int u=0;u<NB;++u){
                #pragma unroll
                for (int d=0;d<3;++d){
                    float tt = t[u][d] + dpp_xor1(t[u][d]);
                    if (!half) ((_Float16*)&u0p[u][d][0])[row2] = (_Float16)(sig0r[u]*tt);
                }
            }
        }
        __syncthreads();
        // S5: u1[d] = sig1 * (V1 @ u0[d])
        {
            float t[NB][3];
            #pragma unroll
            for (int u=0;u<NB;++u){
                const float4* q0 = (const float4*)&u0p[u][0][0] + half*8;
                const float4* q1 = (const float4*)&u0p[u][1][0] + half*8;
                const float4* q2 = (const float4*)&u0p[u][2][0] + half*8;
                float t0=0.f,t1=0.f,t2=0.f;
                #pragma unroll
                for (int k=0;k<8;k++){ t0=dot2q(v1p4[k],q0[k],t0); t1=dot2q(v1p4[k],q1[k],t1); t2=dot2q(v1p4[k],q2[k],t2); }
                t[u][0]=t0; t[u][1]=t1; t[u][2]=t2;
            }
            #pragma unroll
            for (int u=0;u<NB;++u){
                #pragma unroll
                for (int d=0;d<3;++d){
                    float tt = t[u][d] + dpp_xor1(t[u][d]);
                    if (!half) ((_Float16*)&u1p[u][d][0])[row2] = (_Float16)(sig1r[u]*tt);
                }
            }
        }
        __syncthreads();
        // S6: Jf[d] = dtan * (V2 @ u1[d]) — skip-diagonal: tangent d only needs output blocks != d.
        // half path (rows 0..127): tid<128 (rows 0..63)  -> tangents {1,2};
        //                          tid>=128 (rows 64..127)-> tangents {0,2}.
        // quad path (rows 128..191): tangents {0,1} only.
        {
            float tl[NB], t2v[NB], s0v[NB], s1v[NB];
            #pragma unroll
            for (int u=0;u<NB;++u){
                const float4* ql = (const float4*)&u1p[u][tlo][0] + half*8;
                const float4* q2 = (const float4*)&u1p[u][2][0]   + half*8;
                float a=0.f, b=0.f;
                #pragma unroll
                for (int k=0;k<8;k++){ a=dot2q(v2p4[k],ql[k],a); b=dot2q(v2p4[k],q2[k],b); }
                tl[u]=a; t2v[u]=b;
                const float4* w0 = (const float4*)&u1p[u][0][0];
                const float4* w1 = (const float4*)&u1p[u][1][0];
                float s0=0.f, s1=0.f;
                #pragma unroll
                for (int j=0;j<4;j++){
                    const int idx = quad*4 + ((quad+j)&3);
                    s0=dot2q(v2q4[j],w0[idx],s0); s1=dot2q(v2q4[j],w1[idx],s1);
                }
                s0v[u]=s0; s1v[u]=s1;
            }
            #pragma unroll
            for (int u=0;u<NB;++u){
                float a = tl[u]  + dpp_xor1(tl[u]);
                float b = t2v[u] + dpp_xor1(t2v[u]);
                if (!half){ JfSh[u][tlo][row2]=dtanA[u]*a; JfSh[u][2][row2]=dtanA[u]*b; }
                float s0 = s0v[u] + dpp_xor1(s0v[u]); s0 += dpp_xor2(s0);
                float s1 = s1v[u] + dpp_xor1(s1v[u]); s1 += dpp_xor2(s1);
                if (!quad){ JfSh[u][0][row4]=dtanB[u]*s0; JfSh[u][1][row4]=dtanB[u]*s1; }
            }
        }
        __syncthreads();
        // S7 + Heun integrate (fp32, waves 0..NB-1) + fp16 y re-pack via DPP
        if (tid < NB*64) {
            const int u = tid>>6, h = tid&63;
            const int win = step >> 3;
            const float dtu = dtsSh[u][step];
            const float s0=slopesSh[u][win][0], s1=slopesSh[u][win][1], s2=slopesSh[u][win][2],
                        s3=slopesSh[u][win][3], s4=slopesSh[u][win][4], s5=slopesSh[u][win][5];
            float kk = mSh[u][h]*s0 + mSh[u][64+h]*s1 + mSh[u][128+h]*s2;
            kk += s3*(JfSh[u][0][64+h]  - JfSh[u][1][h]);
            kk += s4*(JfSh[u][0][128+h] - JfSh[u][2][h]);
            kk += s5*(JfSh[u][1][128+h] - JfSh[u][2][64+h]);
            if (first){
                k1Sh[u][h] = kk;
                float y2 = ySh[u][h] + dtu*kk;
                float p = dpp_xor1(y2);
                if (!(h&1)) y2p[u][h>>1] = pack2(y2, p);
            } else {
                float yn = ySh[u][h] + 0.5f*dtu*(k1Sh[u][h] + kk);
                ySh[u][h] = yn;
                float p = dpp_xor1(yn);
                if (!(h&1)) yp[u][h>>1] = pack2(yn, p);
            }
        }
        __syncthreads();
    };

    // ---- projection (both batches) ----
    auto proj = [&](int stp) {
        const float4* rr = (const float4*)(RSh + prow*68 + poct*8);
        float4 r0 = rr[0], r1 = rr[1];
        float p[NB];
        #pragma unroll
        for (int u=0;u<NB;++u){
            const float4* yy = (const float4*)(ySh[u] + poct*8);
            float a=0.f; DOT4(a,r0,yy[0]); DOT4(a,r1,yy[1]); p[u]=a;
        }
        #pragma unroll
        for (int u=0;u<NB;++u){
            float a = p[u];
            a += dpp_xor1(a);
            a += dpp_xor2(a);
            a += dpp_hmir(a);    // lane 0 <- lane 7 (quad{4..7} sum); lane 8 <- lane 15 — valid at poct==0
            if (!poct) out[(size_t)((bA+u)*TT + stp)*OUTD + prow] = tanh_f(a + rbp);
        }
    };

    // ---- Heun scan ----
    for (int step=0; step<NSTEP; ++step) {
        proj(step);
        Feval(1, step);
        Feval(0, step);
    }
    proj(NSTEP);
}

extern "C" void kernel_launch(void* const* d_in, const int* in_sizes, int n_in,
                              void* d_out, int out_size, void* d_ws, size_t ws_size,
                              hipStream_t stream) {
    const float* ts = (const float*)d_in[0];
    const float* x  = (const float*)d_in[1];
    const float* W0 = (const float*)d_in[2];
    const float* b0 = (const float*)d_in[3];
    const float* W1 = (const float*)d_in[4];
    const float* b1 = (const float*)d_in[5];
    const float* W2 = (const float*)d_in[6];
    const float* b2 = (const float*)d_in[7];
    const float* V0 = (const float*)d_in[8];
    const float* c0 = (const float*)d_in[9];
    const float* V1 = (const float*)d_in[10];
    const float* c1 = (const float*)d_in[11];
    const float* V2 = (const float*)d_in[12];
    const float* c2 = (const float*)d_in[13];
    const float* R  = (const float*)d_in[14];
    const float* rb = (const float*)d_in[15];
    float* out = (float*)d_out;

    ncde_solve<<<dim3(BB/NB), dim3(256), 0, stream>>>(
        ts, x, W0, b0, W1, b1, W2, b2, V0, c0, V1, c1, V2, c2, R, rb, out);
}